// Round 5
// baseline (308.067 us; speedup 1.0000x reference)
//
#include <hip/hip_runtime.h>
#include <hip/hip_fp16.h>

#define S_LEN 2048
#define NH 16
#define DK 64
#define DM 1024
#define NB 2
#define QKV_SZ (NB * NH * S_LEN * DK)  // 4194304 halfs per tensor

typedef _Float16 half8 __attribute__((ext_vector_type(8)));
typedef _Float16 half4v __attribute__((ext_vector_type(4)));
typedef __fp16 fp16x2 __attribute__((ext_vector_type(2)));
typedef float f32x4 __attribute__((ext_vector_type(4)));

// pack 4 f32 -> 4 f16 (rtz) as one 64-bit value
static __device__ __forceinline__ half4v pack4(const f32x4 v) {
  fp16x2 lo = __builtin_amdgcn_cvt_pkrtz(v[0], v[1]);
  fp16x2 hi = __builtin_amdgcn_cvt_pkrtz(v[2], v[3]);
  half4v r;
  ((fp16x2*)&r)[0] = lo;
  ((fp16x2*)&r)[1] = hi;
  return r;
}

#define GLL(gp, lp)                                                              \
  __builtin_amdgcn_global_load_lds(                                              \
      (const __attribute__((address_space(1))) unsigned int*)(gp),               \
      (__attribute__((address_space(3))) unsigned int*)(lp), 16, 0, 0)

// ---------------- conversion / prep kernels ----------------

__global__ __launch_bounds__(256) void conv_f32_f16(const float* __restrict__ in,
                                                    _Float16* __restrict__ out, int n4) {
  int i = blockIdx.x * 256 + threadIdx.x;
  if (i >= n4) return;
  float4 v = ((const float4*)in)[i];
  half4v o;
  o[0] = (_Float16)v.x; o[1] = (_Float16)v.y; o[2] = (_Float16)v.z; o[3] = (_Float16)v.w;
  ((half4v*)out)[i] = o;
}

// z<4: Wt[n][k] = (f16)(scale * W[k][n]); z==4: bias table build.
__global__ __launch_bounds__(256) void prep_kernel(
    const float* __restrict__ Wq, const float* __restrict__ Wk,
    const float* __restrict__ Wv, const float* __restrict__ Wo,
    _Float16* __restrict__ Wqkvt, _Float16* __restrict__ Wot,
    const float* __restrict__ table, float* __restrict__ btab) {
  int z = blockIdx.z;
  int tx = threadIdx.x, ty = threadIdx.y;
  if (z == 4) {
    // btab[h][r] = log2(e) * table[bucket(r-2047)][h], r in [0,4095)
    int bid = blockIdx.y * 32 + blockIdx.x;
    if (bid >= 256) return;
    int i = bid * 256 + ty * 32 + tx;
    if (i >= NH * 4095) return;
    int h = i / 4095, r = i - h * 4095;
    int rel = r - 2047;              // rel = k - q
    int bucket = rel > 0 ? 16 : 0;
    int a = rel < 0 ? -rel : rel;
    if (a < 8) {
      bucket += a;
    } else {
      int lg = 31 - __clz(a * a);    // floor(2*log2(a))
      int large = 8 + (lg - 6);
      bucket += (large < 15 ? large : 15);
    }
    btab[i] = table[bucket * NH + h] * 1.44269504f;
    return;
  }
  __shared__ float tile[32][33];
  const float* W = (z == 0) ? Wq : (z == 1) ? Wk : (z == 2) ? Wv : Wo;
  _Float16* Wt = (z < 3) ? (Wqkvt + (size_t)z * 1048576) : Wot;
  float scale = (z == 0) ? 1.44269504f : 1.0f;  // fold log2(e) into Q path
  int nx = blockIdx.x * 32 + tx;
  int ky = blockIdx.y * 32;
#pragma unroll
  for (int i = 0; i < 32; i += 8) tile[ty + i][tx] = W[(size_t)(ky + ty + i) * DM + nx];
  __syncthreads();
  int kx = ky + tx;
  int ny = blockIdx.x * 32;
#pragma unroll
  for (int i = 0; i < 32; i += 8)
    Wt[(size_t)(ny + ty + i) * DM + kx] = (_Float16)(tile[tx][ty + i] * scale);
}

// ---------------- fp16 MFMA GEMM: C = A(MxK) @ Bt(NxK)^T ----------------
// MODE 0: scatter f16 into Q[b,h,s,d] | K[b,h,s,d] | V^T[b,h,d,s]; MODE 1: f32 row-major.
// For Q/K tiles and MODE 1 the MFMA operands are swapped so the 4 accumulator
// regs hold 4 consecutive d/col values -> vectorized stores.
template <int MODE>
__global__ __launch_bounds__(256) void gemm_f16(const _Float16* __restrict__ A,
                                                const _Float16* __restrict__ Bt,
                                                void* __restrict__ Cout,
                                                int M, int N, int K) {
  __shared__ _Float16 As[128 * 32];  // swizzled (no pad; global_load_lds)
  __shared__ _Float16 Bs[128 * 32];
  const int t = threadIdx.x;
  const int m0 = blockIdx.y * 128, n0 = blockIdx.x * 128;
  const int w = t >> 6, lane = t & 63, l15 = lane & 15, quad = lane >> 4;
  const int wr = (w >> 1) * 64, wc = (w & 1) * 64;
  const int swz = (quad ^ (l15 & 3)) * 8;
  const bool swapped = (MODE == 1) || (n0 < 2048);  // Q/K tiles & out-proj

  f32x4 acc[4][4];
#pragma unroll
  for (int i = 0; i < 4; i++)
#pragma unroll
    for (int j = 0; j < 4; j++) acc[i][j] = (f32x4){0.f, 0.f, 0.f, 0.f};

  for (int k0 = 0; k0 < K; k0 += 32) {
    __syncthreads();
#pragma unroll
    for (int i = 0; i < 2; i++) {
      int id = t + 256 * i;
      int row = id >> 2, c = id & 3;
      int cg = c ^ (row & 3);
      GLL(A + (size_t)(m0 + row) * K + k0 + cg * 8, (char*)As + id * 16);
      GLL(Bt + (size_t)(n0 + row) * K + k0 + cg * 8, (char*)Bs + id * 16);
    }
    __syncthreads();
    half8 af[4], bf[4];
#pragma unroll
    for (int i = 0; i < 4; i++) af[i] = *(const half8*)(As + (wr + i * 16 + l15) * 32 + swz);
#pragma unroll
    for (int i = 0; i < 4; i++) bf[i] = *(const half8*)(Bs + (wc + i * 16 + l15) * 32 + swz);
    if (swapped) {
#pragma unroll
      for (int i = 0; i < 4; i++)
#pragma unroll
        for (int j = 0; j < 4; j++)
          acc[i][j] = __builtin_amdgcn_mfma_f32_16x16x32_f16(bf[j], af[i], acc[i][j], 0, 0, 0);
    } else {
#pragma unroll
      for (int i = 0; i < 4; i++)
#pragma unroll
        for (int j = 0; j < 4; j++)
          acc[i][j] = __builtin_amdgcn_mfma_f32_16x16x32_f16(af[i], bf[j], acc[i][j], 0, 0, 0);
    }
  }

#pragma unroll
  for (int i = 0; i < 4; i++)
#pragma unroll
    for (int j = 0; j < 4; j++) {
      if (MODE == 1) {
        // swapped: lane row = s (l15), regs = 4 consecutive out-cols
        int srow = m0 + wr + i * 16 + l15;
        int col0 = n0 + wc + j * 16 + quad * 4;
        *(f32x4*)((float*)Cout + (size_t)srow * N + col0) = acc[i][j];
      } else if (n0 < 2048) {
        // swapped: regs = 4 consecutive d within one head
        int srow = m0 + wr + i * 16 + l15;
        int col0 = n0 + wc + j * 16 + quad * 4;
        int which = col0 >> 10, rem = col0 & 1023, hh = rem >> 6, dd = rem & 63;
        int bb = srow >> 11, ss = srow & 2047;
        _Float16* base = (_Float16*)Cout;
        *(half4v*)(base + (size_t)which * QKV_SZ +
                   ((size_t)((bb * NH + hh) * S_LEN) + ss) * DK + dd) = pack4(acc[i][j]);
      } else {
        // V (unswapped): regs = 4 consecutive s -> transposed store [b,h,d,s]
        int row0 = m0 + wr + i * 16 + quad * 4;
        int col = n0 + wc + j * 16 + l15;
        int rem = col & 1023, hh = rem >> 6, dd = rem & 63;
        int bb = row0 >> 11, ss = row0 & 2047;
        _Float16* base = (_Float16*)Cout;
        *(half4v*)(base + (size_t)2 * QKV_SZ +
                   ((size_t)((bb * NH + hh) * DK + dd)) * S_LEN + ss) = pack4(acc[i][j]);
      }
    }
}

// ---------------- flash attention (S^T, split-key waves, no staging) ----------------
// grid (S/64, H, B) = 1024 blocks, block 256 = 4 waves.
// Block covers 64 q; wave w owns key stripe [128*it + 32w, +32), it = 0..15.
// K and V^T fragments load DIRECTLY from global (L2). No barriers in main loop.
// Per-wave online softmax over its keys; split-softmax merge at the end.
__global__ __launch_bounds__(256, 3) void attn_kernel(
    const _Float16* __restrict__ Q, const _Float16* __restrict__ K,
    const _Float16* __restrict__ Vt, const float* __restrict__ btab,
    _Float16* __restrict__ attn_out) {
  __shared__ __align__(16) char smem[35840];
  _Float16* Ps = (_Float16*)smem;          // loop: [4 waves][64 q][32 key] (16 KB)
  float* slab = (float*)(smem + 16384);    // loop: bias, rel = i-256 (2 KB)
  float* obuf = (float*)smem;              // merge: 2 x 64x64 f32 (32 KB)
  float* mlbuf = (float*)(smem + 32768);   // merge: [4 waves][m,l][64 q] (2 KB)

  const int t = threadIdx.x;
  const int Q0 = blockIdx.x * 64;
  const int h = blockIdx.y, b = blockIdx.z;
  const int w = t >> 6, lane = t & 63, l15 = lane & 15, quad = lane >> 4;
  const int sw3 = l15 & 3;

  const _Float16* Qb = Q + (size_t)(b * NH + h) * S_LEN * DK;
  const _Float16* Kb = K + (size_t)(b * NH + h) * S_LEN * DK;
  const _Float16* Vb = Vt + (size_t)(b * NH + h) * S_LEN * DK;  // [d][s]

  for (int i = t; i < 512; i += 256) slab[i] = btab[h * 4095 + 1791 + i];

  // Q B-fragments (B[k=d][n=q]) held in registers for the whole kernel
  half8 qf[4][2];
#pragma unroll
  for (int qt = 0; qt < 4; qt++)
#pragma unroll
    for (int dh = 0; dh < 2; dh++)
      qf[qt][dh] =
          *(const half8*)(Qb + (size_t)(Q0 + qt * 16 + l15) * DK + dh * 32 + quad * 8);

  f32x4 o[4][4];  // [dt][qt], O^T: row=d(reg), col=q(l15)
#pragma unroll
  for (int dt = 0; dt < 4; dt++)
#pragma unroll
    for (int qt = 0; qt < 4; qt++) o[dt][qt] = (f32x4){0.f, 0.f, 0.f, 0.f};
  float m_[4] = {-INFINITY, -INFINITY, -INFINITY, -INFINITY};
  float l_[4] = {0.f, 0.f, 0.f, 0.f};

  _Float16* Pw = Ps + w * 2048;  // this wave's 64x32 P tile

  __syncthreads();  // slab visible to all waves

  for (int it = 0; it < 16; it++) {
    const int ks0 = it * 128 + w * 32;  // wave's key stripe base
    const int dk = ks0 - Q0;
    const bool farneg = (dk <= -159);   // all rel <= -128
    const bool farpos = (dk >= 191);    // all rel >= +128
    const bool nearc = !(farneg || farpos);
    const float cb = farneg ? slab[128] : slab[384];

    // K A-frags (A[m=key][k=d]) and V^T A-frags (A[m=d][k=key]) from global/L2
    half8 kf[2][2], vf[4];
#pragma unroll
    for (int kt = 0; kt < 2; kt++)
#pragma unroll
      for (int dh = 0; dh < 2; dh++)
        kf[kt][dh] =
            *(const half8*)(Kb + (size_t)(ks0 + kt * 16 + l15) * DK + dh * 32 + quad * 8);
#pragma unroll
    for (int dt = 0; dt < 4; dt++)
      vf[dt] = *(const half8*)(Vb + (size_t)(dt * 16 + l15) * S_LEN + ks0 + quad * 8);

#pragma unroll
    for (int qt = 0; qt < 4; qt++) {
      // S^T accumulators: init with bias (near) or zero (far; const bias via m-shift)
      f32x4 st[2];
      if (nearc) {
#pragma unroll
        for (int kt = 0; kt < 2; kt++) {
          int i0 = dk + kt * 16 + quad * 4 - qt * 16 - l15 + 256;
          f32x4 v;
          v[0] = slab[i0]; v[1] = slab[i0 + 1]; v[2] = slab[i0 + 2]; v[3] = slab[i0 + 3];
          st[kt] = v;
        }
      } else {
        st[0] = (f32x4){0.f, 0.f, 0.f, 0.f};
        st[1] = (f32x4){0.f, 0.f, 0.f, 0.f};
      }
#pragma unroll
      for (int kt = 0; kt < 2; kt++)
#pragma unroll
        for (int dh = 0; dh < 2; dh++)
          st[kt] = __builtin_amdgcn_mfma_f32_16x16x32_f16(kf[kt][dh], qf[qt][dh], st[kt],
                                                          0, 0, 0);

      // online softmax (per-lane state, q = qt*16 + l15)
      float cm = fmaxf(fmaxf(st[0][0], st[0][1]), fmaxf(st[0][2], st[0][3]));
      cm = fmaxf(cm, fmaxf(fmaxf(st[1][0], st[1][1]), fmaxf(st[1][2], st[1][3])));
      cm = fmaxf(cm, __shfl_xor(cm, 16));
      cm = fmaxf(cm, __shfl_xor(cm, 32));
      float mc = nearc ? cm : cm + cb;
      if (__any(mc > m_[qt])) {
        float mnew = fmaxf(m_[qt], mc);
        float alpha = __builtin_amdgcn_exp2f(m_[qt] - mnew);
        m_[qt] = mnew;
        l_[qt] *= alpha;
#pragma unroll
        for (int dt = 0; dt < 4; dt++) o[dt][qt] *= alpha;
      }
      float msub = nearc ? m_[qt] : m_[qt] - cb;
#pragma unroll
      for (int kt = 0; kt < 2; kt++) {
        f32x4 p;
#pragma unroll
        for (int r = 0; r < 4; r++) p[r] = __builtin_amdgcn_exp2f(st[kt][r] - msub);
        l_[qt] += (p[0] + p[1]) + (p[2] + p[3]);
        int g = kt * 2 + (quad >> 1);
        *(half4v*)(&Pw[(qt * 16 + l15) * 32 + ((g ^ sw3) << 3) + ((quad & 1) << 2)]) =
            pack4(p);
      }
    }
    __asm__ volatile("s_waitcnt lgkmcnt(0)" ::: "memory");  // wave-local P RAW

    // O^T += V^T P^T  (B-frag of P^T: lane q=l15, keys quad*8..+8)
    half8 pf[4];
#pragma unroll
    for (int qt = 0; qt < 4; qt++)
      pf[qt] = *(const half8*)(&Pw[(qt * 16 + l15) * 32 + ((quad ^ sw3) << 3)]);
#pragma unroll
    for (int dt = 0; dt < 4; dt++)
#pragma unroll
      for (int qt = 0; qt < 4; qt++)
        o[dt][qt] = __builtin_amdgcn_mfma_f32_16x16x32_f16(vf[dt], pf[qt], o[dt][qt],
                                                           0, 0, 0);
  }

  // -------- split-softmax merge across the 4 waves --------
#pragma unroll
  for (int qt = 0; qt < 4; qt++) {  // reduce l over quads (m already quad-uniform)
    l_[qt] += __shfl_xor(l_[qt], 16);
    l_[qt] += __shfl_xor(l_[qt], 32);
  }
  __syncthreads();  // everyone done with Ps/slab; smem repurposed
  if (quad == 0) {
#pragma unroll
    for (int qt = 0; qt < 4; qt++) {
      mlbuf[(w * 2 + 0) * 64 + qt * 16 + l15] = m_[qt];
      mlbuf[(w * 2 + 1) * 64 + qt * 16 + l15] = l_[qt];
    }
  }
  __syncthreads();
  float aw[4], invL[4];
#pragma unroll
  for (int qt = 0; qt < 4; qt++) {
    int q = qt * 16 + l15;
    float M = mlbuf[0 * 64 + q];
#pragma unroll
    for (int v = 1; v < 4; v++) M = fmaxf(M, mlbuf[(v * 2) * 64 + q]);
    float L = 0.f;
#pragma unroll
    for (int v = 0; v < 4; v++)
      L += mlbuf[(v * 2 + 1) * 64 + q] * __builtin_amdgcn_exp2f(mlbuf[(v * 2) * 64 + q] - M);
    aw[qt] = __builtin_amdgcn_exp2f(m_[qt] - M);
    invL[qt] = 1.0f / L;
  }
#pragma unroll
  for (int dt = 0; dt < 4; dt++)
#pragma unroll
    for (int qt = 0; qt < 4; qt++) o[dt][qt] *= aw[qt];

  // tree-reduce O across waves via obuf (swizzled [q][d] f32 tiles)
#define OIDX(dt, qt) (((qt) * 16 + l15) * 64 + ((((dt) * 4 + quad) ^ ((qt * 16 + l15) & 15)) << 2))
  if (w & 1) {
    float* ob = obuf + (w >> 1) * 4096;
#pragma unroll
    for (int dt = 0; dt < 4; dt++)
#pragma unroll
      for (int qt = 0; qt < 4; qt++) *(f32x4*)(&ob[OIDX(dt, qt)]) = o[dt][qt];
  }
  __syncthreads();
  if (!(w & 1)) {
    float* ob = obuf + (w >> 1) * 4096;
#pragma unroll
    for (int dt = 0; dt < 4; dt++)
#pragma unroll
      for (int qt = 0; qt < 4; qt++) o[dt][qt] += *(f32x4*)(&ob[OIDX(dt, qt)]);
  }
  __syncthreads();
  if (w == 2) {
#pragma unroll
    for (int dt = 0; dt < 4; dt++)
#pragma unroll
      for (int qt = 0; qt < 4; qt++) *(f32x4*)(&obuf[OIDX(dt, qt)]) = o[dt][qt];
  }
  __syncthreads();
  if (w == 0) {
#pragma unroll
    for (int qt = 0; qt < 4; qt++) {
      int q = Q0 + qt * 16 + l15;
#pragma unroll
      for (int dt = 0; dt < 4; dt++) {
        f32x4 ov = (o[dt][qt] + *(f32x4*)(&obuf[OIDX(dt, qt)])) * invL[qt];
        *(half4v*)(attn_out + ((size_t)(b * S_LEN + q)) * DM + h * DK + dt * 16 + quad * 4) =
            pack4(ov);
      }
    }
  }
#undef OIDX
}

// ---------------- launch ----------------
extern "C" void kernel_launch(void* const* d_in, const int* in_sizes, int n_in,
                              void* d_out, int out_size, void* d_ws, size_t ws_size,
                              hipStream_t stream) {
  const float* hs  = (const float*)d_in[0];
  const float* Wq  = (const float*)d_in[1];
  const float* Wk  = (const float*)d_in[2];
  const float* Wv  = (const float*)d_in[3];
  const float* Wo  = (const float*)d_in[4];
  const float* tbl = (const float*)d_in[5];
  float* out = (float*)d_out;
  char* ws = (char*)d_ws;

  _Float16* Xh    = (_Float16*)(ws);                    // 8 MB
  _Float16* Wqkvt = (_Float16*)(ws + (8u << 20));       // 6 MB (Wq|Wk|Wv transposed)
  _Float16* Wot   = (_Float16*)(ws + (14u << 20));      // 2 MB
  _Float16* Qd    = (_Float16*)(ws + (16u << 20));      // Q | K | V^T, 8 MB each
  _Float16* Ah    = (_Float16*)(ws + (40u << 20));      // 8 MB attention out (b,s,h*d)
  float*    btab  = (float*)(ws + (48u << 20));         // 16*4095 f32
  _Float16* Kd    = Qd + (size_t)QKV_SZ;
  _Float16* Vd    = Qd + (size_t)2 * QKV_SZ;

  conv_f32_f16<<<4096, 256, 0, stream>>>(hs, Xh, (NB * S_LEN * DM) / 4);
  prep_kernel<<<dim3(32, 32, 5), dim3(32, 8), 0, stream>>>(Wq, Wk, Wv, Wo, Wqkvt, Wot,
                                                           tbl, btab);
  gemm_f16<0><<<dim3(24, 32), 256, 0, stream>>>(Xh, Wqkvt, (void*)Qd, NB * S_LEN, 3 * DM, DM);
  attn_kernel<<<dim3(S_LEN / 64, NH, NB), 256, 0, stream>>>(Qd, Kd, Vd, btab, Ah);
  gemm_f16<1><<<dim3(8, 32), 256, 0, stream>>>(Ah, Wot, (void*)out, NB * S_LEN, DM, DM);
}

// Round 6
// 219.785 us; speedup vs baseline: 1.4017x; 1.4017x over previous
//
#include <hip/hip_runtime.h>
#include <hip/hip_fp16.h>

#define S_LEN 2048
#define NH 16
#define DK 64
#define DM 1024
#define NB 2
#define QKV_SZ (NB * NH * S_LEN * DK)  // 4194304 halfs per tensor
#define HSTRIDE (S_LEN * DK)           // 131072 halfs per (b,h)

typedef _Float16 half8 __attribute__((ext_vector_type(8)));
typedef _Float16 half4v __attribute__((ext_vector_type(4)));
typedef __fp16 fp16x2 __attribute__((ext_vector_type(2)));
typedef float f32x4 __attribute__((ext_vector_type(4)));

// pack 4 f32 -> 4 f16 (rtz) as one 64-bit value
static __device__ __forceinline__ half4v pack4(const f32x4 v) {
  fp16x2 lo = __builtin_amdgcn_cvt_pkrtz(v[0], v[1]);
  fp16x2 hi = __builtin_amdgcn_cvt_pkrtz(v[2], v[3]);
  half4v r;
  ((fp16x2*)&r)[0] = lo;
  ((fp16x2*)&r)[1] = hi;
  return r;
}

#define GLL(gp, lp)                                                              \
  __builtin_amdgcn_global_load_lds(                                              \
      (const __attribute__((address_space(1))) unsigned int*)(gp),               \
      (__attribute__((address_space(3))) unsigned int*)(lp), 16, 0, 0)

// Fragment-linear layouts (per (b,h), base = (b*NH+h)*HSTRIDE):
//  Q,K :  lin = (s>>4)*1024 + ((d>>5)*4 + ((d>>3)&3))*128 + (s&15)*8 + (d&7)
//  V^T :  lin = (s>>6)*4096 + (((d>>4)*2 + ((s>>5)&1))*4 + ((s>>3)&3))*128
//               + (d&15)*8 + (s&7)
// A wave's MFMA fragment load = one contiguous 1KB dwordx4 burst.

// ---------------- fused prep: conv + 4 transposes + bias table ----------------
// grid (32,32,9), block (32,8).  z<4: W transpose; z==4: bias; z>=5: f32->f16 conv.
__global__ __launch_bounds__(256) void prep_kernel(
    const float* __restrict__ hs, const float* __restrict__ Wq,
    const float* __restrict__ Wk, const float* __restrict__ Wv,
    const float* __restrict__ Wo, _Float16* __restrict__ Xh,
    _Float16* __restrict__ Wqkvt, _Float16* __restrict__ Wot,
    const float* __restrict__ table, float* __restrict__ btab) {
  int z = blockIdx.z;
  int tx = threadIdx.x, ty = threadIdx.y;
  if (z >= 5) {  // conv: 4 slices x 1024 blocks x 256 threads x float4
    int i = (((z - 5) << 10) + (int)(blockIdx.y * 32 + blockIdx.x)) * 256 + ty * 32 + tx;
    float4 v = ((const float4*)hs)[i];
    half4v o;
    o[0] = (_Float16)v.x; o[1] = (_Float16)v.y; o[2] = (_Float16)v.z; o[3] = (_Float16)v.w;
    ((half4v*)Xh)[i] = o;
    return;
  }
  if (z == 4) {
    // btab[h][r] = log2(e) * table[bucket(r-2047)][h], r in [0,4095)
    int i = (int)(blockIdx.y * 32 + blockIdx.x) * 256 + ty * 32 + tx;
    if (i >= NH * 4095) return;
    int h = i / 4095, r = i - h * 4095;
    int rel = r - 2047;              // rel = k - q
    int bucket = rel > 0 ? 16 : 0;
    int a = rel < 0 ? -rel : rel;
    if (a < 8) {
      bucket += a;
    } else {
      int lg = 31 - __clz(a * a);    // floor(2*log2(a))
      int large = 8 + (lg - 6);
      bucket += (large < 15 ? large : 15);
    }
    btab[i] = table[bucket * NH + h] * 1.44269504f;
    return;
  }
  __shared__ float tile[32][33];
  const float* W = (z == 0) ? Wq : (z == 1) ? Wk : (z == 2) ? Wv : Wo;
  _Float16* Wt = (z < 3) ? (Wqkvt + (size_t)z * 1048576) : Wot;
  float scale = (z == 0) ? 1.44269504f : 1.0f;  // fold log2(e) into Q path
  int nx = blockIdx.x * 32 + tx;
  int ky = blockIdx.y * 32;
#pragma unroll
  for (int i = 0; i < 32; i += 8) tile[ty + i][tx] = W[(size_t)(ky + ty + i) * DM + nx];
  __syncthreads();
  int kx = ky + tx;
  int ny = blockIdx.x * 32;
#pragma unroll
  for (int i = 0; i < 32; i += 8)
    Wt[(size_t)(ny + ty + i) * DM + kx] = (_Float16)(tile[tx][ty + i] * scale);
}

// ---------------- QKV GEMM: [4096x1024] @ [3072x1024]^T, fragment-scatter ----------------
__global__ __launch_bounds__(256) void gemm_qkv(const _Float16* __restrict__ A,
                                                const _Float16* __restrict__ Bt,
                                                _Float16* __restrict__ QKV) {
  __shared__ _Float16 As[128 * 32];  // swizzled (no pad; global_load_lds)
  __shared__ _Float16 Bs[128 * 32];
  const int K = DM;
  const int t = threadIdx.x;
  const int m0 = blockIdx.y * 128, n0 = blockIdx.x * 128;
  const int w = t >> 6, lane = t & 63, l15 = lane & 15, quad = lane >> 4;
  const int wr = (w >> 1) * 64, wc = (w & 1) * 64;
  const int swz = (quad ^ (l15 & 3)) * 8;
  const bool swapped = (n0 < 2048);  // Q/K cols; V cols >= 2048

  f32x4 acc[4][4];
#pragma unroll
  for (int i = 0; i < 4; i++)
#pragma unroll
    for (int j = 0; j < 4; j++) acc[i][j] = (f32x4){0.f, 0.f, 0.f, 0.f};

  for (int k0 = 0; k0 < K; k0 += 32) {
    __syncthreads();
#pragma unroll
    for (int i = 0; i < 2; i++) {
      int id = t + 256 * i;
      int row = id >> 2, c = id & 3;
      int cg = c ^ (row & 3);
      GLL(A + (size_t)(m0 + row) * K + k0 + cg * 8, (char*)As + id * 16);
      GLL(Bt + (size_t)(n0 + row) * K + k0 + cg * 8, (char*)Bs + id * 16);
    }
    __syncthreads();
    half8 af[4], bf[4];
#pragma unroll
    for (int i = 0; i < 4; i++) af[i] = *(const half8*)(As + (wr + i * 16 + l15) * 32 + swz);
#pragma unroll
    for (int i = 0; i < 4; i++) bf[i] = *(const half8*)(Bs + (wc + i * 16 + l15) * 32 + swz);
    if (swapped) {
#pragma unroll
      for (int i = 0; i < 4; i++)
#pragma unroll
        for (int j = 0; j < 4; j++)
          acc[i][j] = __builtin_amdgcn_mfma_f32_16x16x32_f16(bf[j], af[i], acc[i][j], 0, 0, 0);
    } else {
#pragma unroll
      for (int i = 0; i < 4; i++)
#pragma unroll
        for (int j = 0; j < 4; j++)
          acc[i][j] = __builtin_amdgcn_mfma_f32_16x16x32_f16(af[i], bf[j], acc[i][j], 0, 0, 0);
    }
  }

#pragma unroll
  for (int i = 0; i < 4; i++)
#pragma unroll
    for (int j = 0; j < 4; j++) {
      if (swapped) {
        // Q/K: lane row = s (l15), regs = 4 consecutive d
        int srow = m0 + wr + i * 16 + l15;
        int col0 = n0 + wc + j * 16 + quad * 4;
        int which = col0 >> 10, rem = col0 & 1023, hh = rem >> 6, dd = rem & 63;
        int bb = srow >> 11, ss = srow & 2047;
        int lin = ((ss >> 4) << 10) + (((dd >> 5) * 4 + ((dd >> 3) & 3)) << 7) +
                  ((ss & 15) << 3) + (dd & 7);
        *(half4v*)(QKV + (size_t)which * QKV_SZ + (size_t)(bb * NH + hh) * HSTRIDE + lin) =
            pack4(acc[i][j]);
      } else {
        // V: regs = 4 consecutive s -> V^T fragment layout
        int row0 = m0 + wr + i * 16 + quad * 4;
        int col = n0 + wc + j * 16 + l15;
        int rem = col & 1023, hh = rem >> 6, dd = rem & 63;
        int bb = row0 >> 11, ss = row0 & 2047;  // ss % 4 == 0
        int lin = ((ss >> 6) << 12) +
                  ((((dd >> 4) * 2 + ((ss >> 5) & 1)) * 4 + ((ss >> 3) & 3)) << 7) +
                  ((dd & 15) << 3) + (ss & 7);
        *(half4v*)(QKV + (size_t)2 * QKV_SZ + (size_t)(bb * NH + hh) * HSTRIDE + lin) =
            pack4(acc[i][j]);
      }
    }
}

// ---------------- flash attention (S^T, fragment-linear global K/V, no staging) ----------------
// grid (S/64, H, B) = 1024 blocks, block 256 = 4 waves; wave w owns q [Q0+16w, +16).
// All K/V/Q fragment loads are contiguous 1KB bursts from global (L2-served).
// LDS: per-wave P round-trip + bias slab only. NO barriers in main loop.
__global__ __launch_bounds__(256, 4) void attn_kernel(
    const _Float16* __restrict__ Qf, const _Float16* __restrict__ Kf,
    const _Float16* __restrict__ Vf, const float* __restrict__ btab,
    _Float16* __restrict__ attn_out) {
  __shared__ _Float16 Ps[4][1024];   // per-wave P [q(16)][key(64)], 16B-XOR swizzled
  __shared__ float slab[512];        // bias for rel in [-256,256), log2e-scaled

  const int t = threadIdx.x;
  const int Q0 = blockIdx.x * 64;
  const int h = blockIdx.y, b = blockIdx.z;
  const int w = t >> 6, lane = t & 63, l15 = lane & 15, quad = lane >> 4;
  const int qw0 = Q0 + w * 16;
  const int sw7 = l15 & 7;
  const size_t hb = (size_t)(b * NH + h) * HSTRIDE;
  const _Float16* Qb = Qf + hb;
  const _Float16* Kb = Kf + hb;
  const _Float16* Vb = Vf + hb;

  for (int i = t; i < 512; i += 256) slab[i] = btab[h * 4095 + 1791 + i];

  // Q B-fragments: contiguous fragment-linear load
  half8 qf[2];
  {
    const _Float16* Qt = Qb + (qw0 >> 4) * 1024 + l15 * 8;
    qf[0] = *(const half8*)(Qt + quad * 128);
    qf[1] = *(const half8*)(Qt + (4 + quad) * 128);
  }

  f32x4 o[4];
#pragma unroll
  for (int dt = 0; dt < 4; dt++) o[dt] = (f32x4){0.f, 0.f, 0.f, 0.f};
  float m_ = -INFINITY, l_ = 0.f;

  __syncthreads();  // slab visible

  for (int k0 = 0; k0 < S_LEN; k0 += 64) {
    // K A-frags and V^T A-frags: contiguous 1KB bursts from global (L2)
    half8 kf[4][2], vf[4][2];
    const _Float16* Kc = Kb + (k0 >> 4) * 1024 + l15 * 8;
    const _Float16* Vc = Vb + (k0 >> 6) * 4096 + l15 * 8;
#pragma unroll
    for (int kt = 0; kt < 4; kt++) {
      kf[kt][0] = *(const half8*)(Kc + kt * 1024 + quad * 128);
      kf[kt][1] = *(const half8*)(Kc + kt * 1024 + (4 + quad) * 128);
    }
#pragma unroll
    for (int dt = 0; dt < 4; dt++) {
      vf[dt][0] = *(const half8*)(Vc + (dt * 8 + quad) * 128);
      vf[dt][1] = *(const half8*)(Vc + (dt * 8 + 4 + quad) * 128);
    }

    const int dk0 = k0 - qw0;
    const bool farneg = (dk0 <= -191);   // all rel <= -128
    const bool farpos = (dk0 >= 143);    // all rel >= +128
    const bool nearc = !(farneg || farpos);
    const float cb = farneg ? slab[128] : slab[384];

    // S^T accumulators: init with bias (near) or zero (far; const bias via m-shift)
    f32x4 st[4];
    if (nearc) {
#pragma unroll
      for (int kt = 0; kt < 4; kt++) {
        int i0 = dk0 + kt * 16 + quad * 4 - l15 + 256;
        f32x4 v;
        v[0] = slab[i0]; v[1] = slab[i0 + 1]; v[2] = slab[i0 + 2]; v[3] = slab[i0 + 3];
        st[kt] = v;
      }
    } else {
#pragma unroll
      for (int kt = 0; kt < 4; kt++) st[kt] = (f32x4){0.f, 0.f, 0.f, 0.f};
    }

#pragma unroll
    for (int kt = 0; kt < 4; kt++)
#pragma unroll
      for (int dh = 0; dh < 2; dh++)
        st[kt] = __builtin_amdgcn_mfma_f32_16x16x32_f16(kf[kt][dh], qf[dh], st[kt], 0, 0, 0);

    // online softmax (per-lane state, q = l15; quads hold disjoint keys)
    float cm = fmaxf(fmaxf(st[0][0], st[0][1]), fmaxf(st[0][2], st[0][3]));
#pragma unroll
    for (int kt = 1; kt < 4; kt++)
      cm = fmaxf(cm, fmaxf(fmaxf(st[kt][0], st[kt][1]), fmaxf(st[kt][2], st[kt][3])));
    cm = fmaxf(cm, __shfl_xor(cm, 16));
    cm = fmaxf(cm, __shfl_xor(cm, 32));
    float mc = nearc ? cm : cm + cb;
    if (__any(mc > m_)) {      // wave-uniform skip when running max unchanged
      float mnew = fmaxf(m_, mc);
      float alpha = __builtin_amdgcn_exp2f(m_ - mnew);
      m_ = mnew;
      l_ *= alpha;
#pragma unroll
      for (int dt = 0; dt < 4; dt++) o[dt] *= alpha;
    }
    float msub = nearc ? m_ : m_ - cb;

    f32x4 lacc = (f32x4){0.f, 0.f, 0.f, 0.f};
#pragma unroll
    for (int kt = 0; kt < 4; kt++) {
      f32x4 p;
#pragma unroll
      for (int r = 0; r < 4; r++) p[r] = __builtin_amdgcn_exp2f(st[kt][r] - msub);
      lacc += p;
      // P[q=l15][key=kt*16+quad*4 ..+4] -> b64, group swizzle g^=(l15&7)
      int g = 2 * kt + (quad >> 1);
      *(half4v*)(&Ps[w][l15 * 64 + ((g ^ sw7) << 3) + ((quad & 1) << 2)]) = pack4(p);
    }
    l_ += (lacc[0] + lacc[1]) + (lacc[2] + lacc[3]);
    __asm__ volatile("s_waitcnt lgkmcnt(0)" ::: "memory");  // wave-local P RAW

    // O^T += V^T P^T : B-frag of P^T reads P[q][key] rows with swizzle
    half8 pf[2];
#pragma unroll
    for (int kh = 0; kh < 2; kh++)
      pf[kh] = *(const half8*)(&Ps[w][l15 * 64 + ((((kh << 2) + quad) ^ sw7) << 3)]);
#pragma unroll
    for (int dt = 0; dt < 4; dt++)
#pragma unroll
      for (int kh = 0; kh < 2; kh++)
        o[dt] = __builtin_amdgcn_mfma_f32_16x16x32_f16(vf[dt][kh], pf[kh], o[dt], 0, 0, 0);
  }

  // finalize: reduce l over quads, normalize, store O^T (4 consecutive d -> b64)
  float lf = l_;
  lf += __shfl_xor(lf, 16);
  lf += __shfl_xor(lf, 32);
  float inv = 1.0f / lf;
  int q = qw0 + l15;
#pragma unroll
  for (int dt = 0; dt < 4; dt++) {
    f32x4 ov = o[dt] * inv;
    *(half4v*)(attn_out + ((size_t)(b * S_LEN + q)) * DM + h * DK + dt * 16 + quad * 4) =
        pack4(ov);
  }
}

// ---------------- output GEMM: [4096x1024] @ [1024x1024]^T -> f32, 64x64 tiles ----------------
__global__ __launch_bounds__(256) void gemm_out(const _Float16* __restrict__ A,
                                                const _Float16* __restrict__ Bt,
                                                float* __restrict__ C) {
  __shared__ _Float16 As[64 * 32];
  __shared__ _Float16 Bs[64 * 32];
  const int K = DM, N = DM;
  const int t = threadIdx.x;
  const int m0 = blockIdx.y * 64, n0 = blockIdx.x * 64;
  const int w = t >> 6, lane = t & 63, l15 = lane & 15, quad = lane >> 4;
  const int wr = (w >> 1) * 32, wc = (w & 1) * 32;
  const int swz = (quad ^ (l15 & 3)) * 8;

  f32x4 acc[2][2];
#pragma unroll
  for (int i = 0; i < 2; i++)
#pragma unroll
    for (int j = 0; j < 2; j++) acc[i][j] = (f32x4){0.f, 0.f, 0.f, 0.f};

  for (int k0 = 0; k0 < K; k0 += 32) {
    __syncthreads();
    {
      int row = t >> 2, c = t & 3;
      int cg = c ^ (row & 3);
      GLL(A + (size_t)(m0 + row) * K + k0 + cg * 8, (char*)As + t * 16);
      GLL(Bt + (size_t)(n0 + row) * K + k0 + cg * 8, (char*)Bs + t * 16);
    }
    __syncthreads();
    half8 af[2], bf[2];
#pragma unroll
    for (int i = 0; i < 2; i++) af[i] = *(const half8*)(As + (wr + i * 16 + l15) * 32 + swz);
#pragma unroll
    for (int j = 0; j < 2; j++) bf[j] = *(const half8*)(Bs + (wc + j * 16 + l15) * 32 + swz);
#pragma unroll
    for (int i = 0; i < 2; i++)
#pragma unroll
      for (int j = 0; j < 2; j++)
        acc[i][j] = __builtin_amdgcn_mfma_f32_16x16x32_f16(bf[j], af[i], acc[i][j], 0, 0, 0);
  }

#pragma unroll
  for (int i = 0; i < 2; i++)
#pragma unroll
    for (int j = 0; j < 2; j++) {
      int srow = m0 + wr + i * 16 + l15;
      int col0 = n0 + wc + j * 16 + quad * 4;
      *(f32x4*)(C + (size_t)srow * N + col0) = acc[i][j];
    }
}

// ---------------- launch ----------------
extern "C" void kernel_launch(void* const* d_in, const int* in_sizes, int n_in,
                              void* d_out, int out_size, void* d_ws, size_t ws_size,
                              hipStream_t stream) {
  const float* hs  = (const float*)d_in[0];
  const float* Wq  = (const float*)d_in[1];
  const float* Wk  = (const float*)d_in[2];
  const float* Wv  = (const float*)d_in[3];
  const float* Wo  = (const float*)d_in[4];
  const float* tbl = (const float*)d_in[5];
  float* out = (float*)d_out;
  char* ws = (char*)d_ws;

  _Float16* Xh    = (_Float16*)(ws);                    // 8 MB
  _Float16* Wqkvt = (_Float16*)(ws + (8u << 20));       // 6 MB (Wq|Wk|Wv transposed)
  _Float16* Wot   = (_Float16*)(ws + (14u << 20));      // 2 MB
  _Float16* Qd    = (_Float16*)(ws + (16u << 20));      // Q | K | V^T frag-linear, 8 MB each
  _Float16* Ah    = (_Float16*)(ws + (40u << 20));      // 8 MB attention out (b,s,h*d)
  float*    btab  = (float*)(ws + (48u << 20));         // 16*4095 f32
  _Float16* Kd    = Qd + (size_t)QKV_SZ;
  _Float16* Vd    = Qd + (size_t)2 * QKV_SZ;

  prep_kernel<<<dim3(32, 32, 9), dim3(32, 8), 0, stream>>>(hs, Wq, Wk, Wv, Wo, Xh,
                                                           Wqkvt, Wot, tbl, btab);
  gemm_qkv<<<dim3(24, 32), 256, 0, stream>>>(Xh, Wqkvt, Qd);
  attn_kernel<<<dim3(S_LEN / 64, NH, NB), 256, 0, stream>>>(Qd, Kd, Vd, btab, Ah);
  gemm_out<<<dim3(16, 64), 256, 0, stream>>>(Ah, Wot, out);
}

// Round 7
// 219.520 us; speedup vs baseline: 1.4034x; 1.0012x over previous
//
#include <hip/hip_runtime.h>
#include <hip/hip_fp16.h>

#define S_LEN 2048
#define NH 16
#define DK 64
#define DM 1024
#define NB 2
#define QKV_SZ (NB * NH * S_LEN * DK)  // 4194304 halfs per tensor
#define HSTRIDE (S_LEN * DK)           // 131072 halfs per (b,h)

typedef _Float16 half8 __attribute__((ext_vector_type(8)));
typedef _Float16 half4v __attribute__((ext_vector_type(4)));
typedef __fp16 fp16x2 __attribute__((ext_vector_type(2)));
typedef float f32x4 __attribute__((ext_vector_type(4)));

// pack 4 f32 -> 4 f16 (rtz) as one 64-bit value
static __device__ __forceinline__ half4v pack4(const f32x4 v) {
  fp16x2 lo = __builtin_amdgcn_cvt_pkrtz(v[0], v[1]);
  fp16x2 hi = __builtin_amdgcn_cvt_pkrtz(v[2], v[3]);
  half4v r;
  ((fp16x2*)&r)[0] = lo;
  ((fp16x2*)&r)[1] = hi;
  return r;
}

#define GLL(gp, lp)                                                              \
  __builtin_amdgcn_global_load_lds(                                              \
      (const __attribute__((address_space(1))) unsigned int*)(gp),               \
      (__attribute__((address_space(3))) unsigned int*)(lp), 16, 0, 0)

// Fragment-linear layouts (per (b,h), base = (b*NH+h)*HSTRIDE):
//  Q,K :  lin = (s>>4)*1024 + ((d>>5)*4 + ((d>>3)&3))*128 + (s&15)*8 + (d&7)
//  V^T :  lin = (s>>6)*4096 + (((d>>4)*2 + ((s>>5)&1))*4 + ((s>>3)&3))*128
//               + (d&15)*8 + (s&7)
// A wave's MFMA fragment load = one contiguous 1KB dwordx4 burst.

// ---------------- fused prep: conv + 4 transposes + bias table ----------------
// grid (32,32,9), block (32,8).  z<4: W transpose; z==4: bias; z>=5: f32->f16 conv.
__global__ __launch_bounds__(256) void prep_kernel(
    const float* __restrict__ hs, const float* __restrict__ Wq,
    const float* __restrict__ Wk, const float* __restrict__ Wv,
    const float* __restrict__ Wo, _Float16* __restrict__ Xh,
    _Float16* __restrict__ Wqkvt, _Float16* __restrict__ Wot,
    const float* __restrict__ table, float* __restrict__ btab) {
  int z = blockIdx.z;
  int tx = threadIdx.x, ty = threadIdx.y;
  if (z >= 5) {  // conv: 4 slices x 1024 blocks x 256 threads x float4
    int i = (((z - 5) << 10) + (int)(blockIdx.y * 32 + blockIdx.x)) * 256 + ty * 32 + tx;
    float4 v = ((const float4*)hs)[i];
    half4v o;
    o[0] = (_Float16)v.x; o[1] = (_Float16)v.y; o[2] = (_Float16)v.z; o[3] = (_Float16)v.w;
    ((half4v*)Xh)[i] = o;
    return;
  }
  if (z == 4) {
    // btab[h][r] = log2(e) * table[bucket(r-2047)][h], r in [0,4095)
    int i = (int)(blockIdx.y * 32 + blockIdx.x) * 256 + ty * 32 + tx;
    if (i >= NH * 4095) return;
    int h = i / 4095, r = i - h * 4095;
    int rel = r - 2047;              // rel = k - q
    int bucket = rel > 0 ? 16 : 0;
    int a = rel < 0 ? -rel : rel;
    if (a < 8) {
      bucket += a;
    } else {
      int lg = 31 - __clz(a * a);    // floor(2*log2(a))
      int large = 8 + (lg - 6);
      bucket += (large < 15 ? large : 15);
    }
    btab[i] = table[bucket * NH + h] * 1.44269504f;
    return;
  }
  __shared__ float tile[32][33];
  const float* W = (z == 0) ? Wq : (z == 1) ? Wk : (z == 2) ? Wv : Wo;
  _Float16* Wt = (z < 3) ? (Wqkvt + (size_t)z * 1048576) : Wot;
  float scale = (z == 0) ? 1.44269504f : 1.0f;  // fold log2(e) into Q path
  int nx = blockIdx.x * 32 + tx;
  int ky = blockIdx.y * 32;
#pragma unroll
  for (int i = 0; i < 32; i += 8) tile[ty + i][tx] = W[(size_t)(ky + ty + i) * DM + nx];
  __syncthreads();
  int kx = ky + tx;
  int ny = blockIdx.x * 32;
#pragma unroll
  for (int i = 0; i < 32; i += 8)
    Wt[(size_t)(ny + ty + i) * DM + kx] = (_Float16)(tile[tx][ty + i] * scale);
}

// ---------------- QKV GEMM: [4096x1024] @ [3072x1024]^T, fragment-scatter ----------------
__global__ __launch_bounds__(256) void gemm_qkv(const _Float16* __restrict__ A,
                                                const _Float16* __restrict__ Bt,
                                                _Float16* __restrict__ QKV) {
  __shared__ _Float16 As[128 * 32];  // swizzled (no pad; global_load_lds)
  __shared__ _Float16 Bs[128 * 32];
  const int K = DM;
  const int t = threadIdx.x;
  const int m0 = blockIdx.y * 128, n0 = blockIdx.x * 128;
  const int w = t >> 6, lane = t & 63, l15 = lane & 15, quad = lane >> 4;
  const int wr = (w >> 1) * 64, wc = (w & 1) * 64;
  const int swz = (quad ^ (l15 & 3)) * 8;
  const bool swapped = (n0 < 2048);  // Q/K cols; V cols >= 2048

  f32x4 acc[4][4];
#pragma unroll
  for (int i = 0; i < 4; i++)
#pragma unroll
    for (int j = 0; j < 4; j++) acc[i][j] = (f32x4){0.f, 0.f, 0.f, 0.f};

  for (int k0 = 0; k0 < K; k0 += 32) {
    __syncthreads();
#pragma unroll
    for (int i = 0; i < 2; i++) {
      int id = t + 256 * i;
      int row = id >> 2, c = id & 3;
      int cg = c ^ (row & 3);
      GLL(A + (size_t)(m0 + row) * K + k0 + cg * 8, (char*)As + id * 16);
      GLL(Bt + (size_t)(n0 + row) * K + k0 + cg * 8, (char*)Bs + id * 16);
    }
    __syncthreads();
    half8 af[4], bf[4];
#pragma unroll
    for (int i = 0; i < 4; i++) af[i] = *(const half8*)(As + (wr + i * 16 + l15) * 32 + swz);
#pragma unroll
    for (int i = 0; i < 4; i++) bf[i] = *(const half8*)(Bs + (wc + i * 16 + l15) * 32 + swz);
    if (swapped) {
#pragma unroll
      for (int i = 0; i < 4; i++)
#pragma unroll
        for (int j = 0; j < 4; j++)
          acc[i][j] = __builtin_amdgcn_mfma_f32_16x16x32_f16(bf[j], af[i], acc[i][j], 0, 0, 0);
    } else {
#pragma unroll
      for (int i = 0; i < 4; i++)
#pragma unroll
        for (int j = 0; j < 4; j++)
          acc[i][j] = __builtin_amdgcn_mfma_f32_16x16x32_f16(af[i], bf[j], acc[i][j], 0, 0, 0);
    }
  }

#pragma unroll
  for (int i = 0; i < 4; i++)
#pragma unroll
    for (int j = 0; j < 4; j++) {
      if (swapped) {
        // Q/K: lane row = s (l15), regs = 4 consecutive d
        int srow = m0 + wr + i * 16 + l15;
        int col0 = n0 + wc + j * 16 + quad * 4;
        int which = col0 >> 10, rem = col0 & 1023, hh = rem >> 6, dd = rem & 63;
        int bb = srow >> 11, ss = srow & 2047;
        int lin = ((ss >> 4) << 10) + (((dd >> 5) * 4 + ((dd >> 3) & 3)) << 7) +
                  ((ss & 15) << 3) + (dd & 7);
        *(half4v*)(QKV + (size_t)which * QKV_SZ + (size_t)(bb * NH + hh) * HSTRIDE + lin) =
            pack4(acc[i][j]);
      } else {
        // V: regs = 4 consecutive s -> V^T fragment layout
        int row0 = m0 + wr + i * 16 + quad * 4;
        int col = n0 + wc + j * 16 + l15;
        int rem = col & 1023, hh = rem >> 6, dd = rem & 63;
        int bb = row0 >> 11, ss = row0 & 2047;  // ss % 4 == 0
        int lin = ((ss >> 6) << 12) +
                  ((((dd >> 4) * 2 + ((ss >> 5) & 1)) * 4 + ((ss >> 3) & 3)) << 7) +
                  ((dd & 15) << 3) + (ss & 7);
        *(half4v*)(QKV + (size_t)2 * QKV_SZ + (size_t)(bb * NH + hh) * HSTRIDE + lin) =
            pack4(acc[i][j]);
      }
    }
}

// ---------------- flash attention: K direct-global + reg prefetch, V via LDS dbuf ----------------
// grid (S/64, H, B) = 1024 blocks, block 256 = 4 waves; wave w owns q [Q0+16w, +16).
// V chunk staged once per block (identity global_load_lds, double-buffered, 1 barrier/chunk).
// K fragments read per-wave from global (frag-linear, L1-amortized across waves).
__global__ __launch_bounds__(256, 3) void attn_kernel(
    const _Float16* __restrict__ Qf, const _Float16* __restrict__ Kf,
    const _Float16* __restrict__ Vf, const float* __restrict__ btab,
    _Float16* __restrict__ attn_out) {
  __shared__ _Float16 Vs[2][4096];   // V^T 64-key panel, frag-linear, dbuf (16 KB)
  __shared__ _Float16 Ps[4][1024];   // per-wave P [q(16)][key(64)], 16B-XOR swizzled
  __shared__ float slab[512];        // bias for rel in [-256,256), log2e-scaled

  const int t = threadIdx.x;
  const int Q0 = blockIdx.x * 64;
  const int h = blockIdx.y, b = blockIdx.z;
  const int w = t >> 6, lane = t & 63, l15 = lane & 15, quad = lane >> 4;
  const int qw0 = Q0 + w * 16;
  const int sw7 = l15 & 7;
  const size_t hb = (size_t)(b * NH + h) * HSTRIDE;
  const _Float16* Qb = Qf + hb;
  const _Float16* Kb = Kf + hb;
  const _Float16* Vb = Vf + hb;

  for (int i = t; i < 512; i += 256) slab[i] = btab[h * 4095 + 1791 + i];

  // Q B-fragments: contiguous fragment-linear load
  half8 qf[2];
  {
    const _Float16* Qt = Qb + (qw0 >> 4) * 1024 + l15 * 8;
    qf[0] = *(const half8*)(Qt + quad * 128);
    qf[1] = *(const half8*)(Qt + (4 + quad) * 128);
  }

  // stage V chunk 0 into Vs[0] (identity copy, async)
  GLL(Vb + t * 8, &Vs[0][t * 8]);
  GLL(Vb + 2048 + t * 8, &Vs[0][t * 8 + 2048]);

  // K lane-base pointer; all frag loads = base + immediate offset
  const _Float16* kp = Kb + quad * 128 + l15 * 8;

  half8 kfa[4][2], kfb[4][2];
#define LOADK(dst, base)                                                   \
  {                                                                        \
    _Pragma("unroll") for (int kt_ = 0; kt_ < 4; kt_++)                    \
      _Pragma("unroll") for (int dh_ = 0; dh_ < 2; dh_++)                  \
        dst[kt_][dh_] = *(const half8*)((base) + kt_ * 1024 + dh_ * 512);  \
  }
  LOADK(kfa, kp);  // prefetch K chunk 0

  f32x4 o[4];
#pragma unroll
  for (int dt = 0; dt < 4; dt++) o[dt] = (f32x4){0.f, 0.f, 0.f, 0.f};
  float m_ = -INFINITY, l_ = 0.f;

  __syncthreads();  // slab + V0 staged (barrier drains vmcnt)

  auto process = [&](int it, int bi, half8 kcur[4][2], half8 knxt[4][2]) {
    // stage V(it+1) + prefetch K(it+1) (both async w.r.t. this chunk's compute)
    if (it + 1 < 32) {
      const _Float16* vsrc = Vb + (it + 1) * 4096 + t * 8;
      GLL(vsrc, &Vs[bi ^ 1][t * 8]);
      GLL(vsrc + 2048, &Vs[bi ^ 1][t * 8 + 2048]);
      LOADK(knxt, kp + (it + 1) * 4096);
    }

    const int dk0 = it * 64 - qw0;
    const bool farneg = (dk0 <= -191);   // all rel <= -128
    const bool farpos = (dk0 >= 143);    // all rel >= +128
    const bool nearc = !(farneg || farpos);
    const float cb = farneg ? slab[128] : slab[384];

    // S^T accumulators: init with bias (near) or zero (far; const bias via m-shift)
    f32x4 st[4];
    if (nearc) {
#pragma unroll
      for (int kt = 0; kt < 4; kt++) {
        int i0 = dk0 + kt * 16 + quad * 4 - l15 + 256;
        f32x4 v;
        v[0] = slab[i0]; v[1] = slab[i0 + 1]; v[2] = slab[i0 + 2]; v[3] = slab[i0 + 3];
        st[kt] = v;
      }
    } else {
#pragma unroll
      for (int kt = 0; kt < 4; kt++) st[kt] = (f32x4){0.f, 0.f, 0.f, 0.f};
    }

#pragma unroll
    for (int kt = 0; kt < 4; kt++)
#pragma unroll
      for (int dh = 0; dh < 2; dh++)
        st[kt] = __builtin_amdgcn_mfma_f32_16x16x32_f16(kcur[kt][dh], qf[dh], st[kt], 0, 0, 0);

    // online softmax (per-lane state, q = l15; quads hold disjoint keys)
    float cm = fmaxf(fmaxf(st[0][0], st[0][1]), fmaxf(st[0][2], st[0][3]));
#pragma unroll
    for (int kt = 1; kt < 4; kt++)
      cm = fmaxf(cm, fmaxf(fmaxf(st[kt][0], st[kt][1]), fmaxf(st[kt][2], st[kt][3])));
    cm = fmaxf(cm, __shfl_xor(cm, 16));
    cm = fmaxf(cm, __shfl_xor(cm, 32));
    float mc = nearc ? cm : cm + cb;
    if (__any(mc > m_)) {      // wave-uniform skip when running max unchanged
      float mnew = fmaxf(m_, mc);
      float alpha = __builtin_amdgcn_exp2f(m_ - mnew);
      m_ = mnew;
      l_ *= alpha;
#pragma unroll
      for (int dt = 0; dt < 4; dt++) o[dt] *= alpha;
    }
    float msub = nearc ? m_ : m_ - cb;

    f32x4 lacc = (f32x4){0.f, 0.f, 0.f, 0.f};
#pragma unroll
    for (int kt = 0; kt < 4; kt++) {
      f32x4 p;
#pragma unroll
      for (int r = 0; r < 4; r++) p[r] = __builtin_amdgcn_exp2f(st[kt][r] - msub);
      lacc += p;
      // P[q=l15][key=kt*16+quad*4 ..+4] -> b64, group swizzle g^=(l15&7)
      int g = 2 * kt + (quad >> 1);
      *(half4v*)(&Ps[w][l15 * 64 + ((g ^ sw7) << 3) + ((quad & 1) << 2)]) = pack4(p);
    }
    l_ += (lacc[0] + lacc[1]) + (lacc[2] + lacc[3]);
    __asm__ volatile("s_waitcnt lgkmcnt(0)" ::: "memory");  // wave-local P RAW

    // O^T += V^T P^T : vf from LDS (staged last chunk), pf from Ps
    half8 pf[2], vf[4][2];
#pragma unroll
    for (int kh = 0; kh < 2; kh++)
      pf[kh] = *(const half8*)(&Ps[w][l15 * 64 + ((((kh << 2) + quad) ^ sw7) << 3)]);
#pragma unroll
    for (int dt = 0; dt < 4; dt++)
#pragma unroll
      for (int kh = 0; kh < 2; kh++)
        vf[dt][kh] = *(const half8*)(&Vs[bi][(dt * 8 + kh * 4 + quad) * 128 + l15 * 8]);
#pragma unroll
    for (int dt = 0; dt < 4; dt++)
#pragma unroll
      for (int kh = 0; kh < 2; kh++)
        o[dt] = __builtin_amdgcn_mfma_f32_16x16x32_f16(vf[dt][kh], pf[kh], o[dt], 0, 0, 0);

    __syncthreads();  // all waves done with Vs[bi]; V(it+1)/K prefetch drained
  };

  for (int it = 0; it < 32; it += 2) {
    process(it, 0, kfa, kfb);
    process(it + 1, 1, kfb, kfa);
  }
#undef LOADK

  // finalize: reduce l over quads, normalize, store O^T (4 consecutive d -> b64)
  float lf = l_;
  lf += __shfl_xor(lf, 16);
  lf += __shfl_xor(lf, 32);
  float inv = 1.0f / lf;
  int q = qw0 + l15;
#pragma unroll
  for (int dt = 0; dt < 4; dt++) {
    f32x4 ov = o[dt] * inv;
    *(half4v*)(attn_out + ((size_t)(b * S_LEN + q)) * DM + h * DK + dt * 16 + quad * 4) =
        pack4(ov);
  }
}

// ---------------- output GEMM: [4096x1024] @ [1024x1024]^T -> f32, 64x64 tiles ----------------
__global__ __launch_bounds__(256) void gemm_out(const _Float16* __restrict__ A,
                                                const _Float16* __restrict__ Bt,
                                                float* __restrict__ C) {
  __shared__ _Float16 As[64 * 32];
  __shared__ _Float16 Bs[64 * 32];
  const int K = DM, N = DM;
  const int t = threadIdx.x;
  const int m0 = blockIdx.y * 64, n0 = blockIdx.x * 64;
  const int w = t >> 6, lane = t & 63, l15 = lane & 15, quad = lane >> 4;
  const int wr = (w >> 1) * 32, wc = (w & 1) * 32;
  const int swz = (quad ^ (l15 & 3)) * 8;

  f32x4 acc[2][2];
#pragma unroll
  for (int i = 0; i < 2; i++)
#pragma unroll
    for (int j = 0; j < 2; j++) acc[i][j] = (f32x4){0.f, 0.f, 0.f, 0.f};

  for (int k0 = 0; k0 < K; k0 += 32) {
    __syncthreads();
    {
      int row = t >> 2, c = t & 3;
      int cg = c ^ (row & 3);
      GLL(A + (size_t)(m0 + row) * K + k0 + cg * 8, (char*)As + t * 16);
      GLL(Bt + (size_t)(n0 + row) * K + k0 + cg * 8, (char*)Bs + t * 16);
    }
    __syncthreads();
    half8 af[2], bf[2];
#pragma unroll
    for (int i = 0; i < 2; i++) af[i] = *(const half8*)(As + (wr + i * 16 + l15) * 32 + swz);
#pragma unroll
    for (int j = 0; j < 2; j++) bf[j] = *(const half8*)(Bs + (wc + j * 16 + l15) * 32 + swz);
#pragma unroll
    for (int i = 0; i < 2; i++)
#pragma unroll
      for (int j = 0; j < 2; j++)
        acc[i][j] = __builtin_amdgcn_mfma_f32_16x16x32_f16(bf[j], af[i], acc[i][j], 0, 0, 0);
  }

#pragma unroll
  for (int i = 0; i < 2; i++)
#pragma unroll
    for (int j = 0; j < 2; j++) {
      int srow = m0 + wr + i * 16 + l15;
      int col0 = n0 + wc + j * 16 + quad * 4;
      *(f32x4*)(C + (size_t)srow * N + col0) = acc[i][j];
    }
}

// ---------------- launch ----------------
extern "C" void kernel_launch(void* const* d_in, const int* in_sizes, int n_in,
                              void* d_out, int out_size, void* d_ws, size_t ws_size,
                              hipStream_t stream) {
  const float* hs  = (const float*)d_in[0];
  const float* Wq  = (const float*)d_in[1];
  const float* Wk  = (const float*)d_in[2];
  const float* Wv  = (const float*)d_in[3];
  const float* Wo  = (const float*)d_in[4];
  const float* tbl = (const float*)d_in[5];
  float* out = (float*)d_out;
  char* ws = (char*)d_ws;

  _Float16* Xh    = (_Float16*)(ws);                    // 8 MB
  _Float16* Wqkvt = (_Float16*)(ws + (8u << 20));       // 6 MB (Wq|Wk|Wv transposed)
  _Float16* Wot   = (_Float16*)(ws + (14u << 20));      // 2 MB
  _Float16* Qd    = (_Float16*)(ws + (16u << 20));      // Q | K | V^T frag-linear, 8 MB each
  _Float16* Ah    = (_Float16*)(ws + (40u << 20));      // 8 MB attention out (b,s,h*d)
  float*    btab  = (float*)(ws + (48u << 20));         // 16*4095 f32
  _Float16* Kd    = Qd + (size_t)QKV_SZ;
  _Float16* Vd    = Qd + (size_t)2 * QKV_SZ;

  prep_kernel<<<dim3(32, 32, 9), dim3(32, 8), 0, stream>>>(hs, Wq, Wk, Wv, Wo, Xh,
                                                           Wqkvt, Wot, tbl, btab);
  gemm_qkv<<<dim3(24, 32), 256, 0, stream>>>(Xh, Wqkvt, Qd);
  attn_kernel<<<dim3(S_LEN / 64, NH, NB), 256, 0, stream>>>(Qd, Kd, Vd, btab, Ah);
  gemm_out<<<dim3(16, 64), 256, 0, stream>>>(Ah, Wot, out);
}